// Round 4
// baseline (443.638 us; speedup 1.0000x reference)
//
#include <hip/hip_runtime.h>

// ---------------------------------------------------------------------------
// RingDilatedAttentionSDPA: B=1, S=8192, E=1024, H=16, D=64
// segments: (len=2048,dil=1), (4096,2), (8192->2048,4); mean of scattered outs
// Pipeline: cvt f32->bf16 ; QKV GEMM -> Q(pre-scaled log2e/8),K,V [h][s][d] ;
// transpose_v -> 3 key-permuted V^T dilation copies ; single flash launch
// computing S^T=K.Q^T and O^T=V^T.P^T (Q register-resident B-operand; packed
// exp2 C-regs ARE the P^T B-frag thanks to the vt key permutation) ; combine ;
// out GEMM.
// R4: BARRIER-FREE flash main loop. Per block-tile the K/V working set is
// 16KB and all 4 wq-waves read identical tiles -> per-CU L1 dedups; LDS
// staging + per-tile barriers were pure overhead keeping 8 waves in lockstep
// (R3: 70% stall, MfmaUtil 30%). K/V fragments now load DIRECTLY from global
// (each K row is exactly one 128B cache line, even dilated); no s_barrier,
// no waitcnt asm, no LDS in the main loop -> waves free-run and 4 waves/SIMD
// overlap different phases. K loads issue before V loads so QK's implicit
// vmcnt leaves V in flight across the exp2 phase. LDS is epilogue-only.
// ---------------------------------------------------------------------------

typedef __attribute__((ext_vector_type(8))) short bf16x8;   // 8 bf16 in 4 VGPRs
typedef __attribute__((ext_vector_type(4))) float f32x4;

#define MFMA(a, b, c) __builtin_amdgcn_mfma_f32_16x16x32_bf16((a), (b), (c), 0, 0, 0)

#if __has_builtin(__builtin_amdgcn_exp2f)
#define EXP2(x) __builtin_amdgcn_exp2f(x)
#else
#define EXP2(x) exp2f(x)
#endif

static __device__ __forceinline__ unsigned short f2bf(float f) {
  unsigned int u = __float_as_uint(f);
  unsigned int r = (u + 0x7FFFu + ((u >> 16) & 1u)) >> 16;  // RNE
  return (unsigned short)r;
}

// ---------------------------- f32 -> bf16 convert --------------------------
__global__ void cvt_f32_bf16(const float* __restrict__ in,
                             unsigned short* __restrict__ out, int n8) {
  int i = blockIdx.x * blockDim.x + threadIdx.x;
  if (i >= n8) return;
  const float4* p = (const float4*)in + (size_t)i * 2;
  float4 a = p[0];
  float4 b = p[1];
  union { bf16x8 v; unsigned short u[8]; } o;
  o.u[0] = f2bf(a.x); o.u[1] = f2bf(a.y); o.u[2] = f2bf(a.z); o.u[3] = f2bf(a.w);
  o.u[4] = f2bf(b.x); o.u[5] = f2bf(b.y); o.u[6] = f2bf(b.z); o.u[7] = f2bf(b.w);
  *((bf16x8*)out + i) = o.v;
}

// ------------------------------- GEMM (C = A.B^T + bias) -------------------
// EPILOGUE 0: qkv [3][16][8192][64] bf16, Q scaled by log2e/8; 1: f32 rowmaj.
template <int EPILOGUE>
__global__ __launch_bounds__(256, 2) void gemm_bt(
    const unsigned short* __restrict__ A, const unsigned short* __restrict__ B,
    const float* __restrict__ bias, void* __restrict__ Cout, int N, int K) {
  __shared__ unsigned short At[128 * 32];
  __shared__ unsigned short Bt[128 * 32];
  const int tid = threadIdx.x;
  const int wave = tid >> 6, lane = tid & 63;
  const int quad = lane >> 4, lc = lane & 15;
  const int wm = (wave >> 1) * 64, wn = (wave & 1) * 64;
  const int m0 = blockIdx.x * 128, n0 = blockIdx.y * 128;

  f32x4 acc[4][4] = {};

  for (int k0 = 0; k0 < K; k0 += 32) {
    __syncthreads();
#pragma unroll
    for (int issue = 0; issue < 2; ++issue) {
      const int cbase = issue * 256 + wave * 64;
      const int c = cbase + lane;
      const int row = c >> 2, col8 = (c & 3) * 8;   // 128 rows x 32 cols
      __builtin_amdgcn_global_load_lds(
          (const __attribute__((address_space(1))) void*)&A[(size_t)(m0 + row) * K + k0 + col8],
          (__attribute__((address_space(3))) void*)&At[cbase * 8], 16, 0, 0);
      __builtin_amdgcn_global_load_lds(
          (const __attribute__((address_space(1))) void*)&B[(size_t)(n0 + row) * K + k0 + col8],
          (__attribute__((address_space(3))) void*)&Bt[cbase * 8], 16, 0, 0);
    }
    __syncthreads();
    bf16x8 af[4], bfr[4];
#pragma unroll
    for (int t = 0; t < 4; ++t)
      af[t] = *(const bf16x8*)&At[(wm + t * 16 + lc) * 32 + quad * 8];
#pragma unroll
    for (int t = 0; t < 4; ++t)
      bfr[t] = *(const bf16x8*)&Bt[(wn + t * 16 + lc) * 32 + quad * 8];
#pragma unroll
    for (int i = 0; i < 4; ++i)
#pragma unroll
      for (int j = 0; j < 4; ++j)
        acc[i][j] = MFMA(af[i], bfr[j], acc[i][j]);
  }

#pragma unroll
  for (int i = 0; i < 4; ++i) {
#pragma unroll
    for (int j = 0; j < 4; ++j) {
      const int gcol = n0 + wn + j * 16 + lc;
      const float bs = bias[gcol];
#pragma unroll
      for (int r = 0; r < 4; ++r) {
        const int grow = m0 + wm + i * 16 + quad * 4 + r;
        const float v = acc[i][j][r] + bs;
        if (EPILOGUE == 0) {
          const int which = gcol >> 10, rem = gcol & 1023;
          const int hh = rem >> 6, d = rem & 63;
          // Q gets 1/sqrt(D) * log2(e) folded in (exp2 softmax downstream)
          const float vs = (which == 0) ? v * 0.18033688f : v;
          ((unsigned short*)Cout)[(((size_t)(which * 16 + hh)) * 8192 + grow) * 64 + d] = f2bf(vs);
        } else {
          ((float*)Cout)[(size_t)grow * N + gcol] = v;
        }
      }
    }
  }
}

// ---------------- V transpose: [h][s][d] -> key-permuted [h][d][n] ---------
// perm within each 32-block: position p holds key 16*((p>>2)&1)+4*(p>>3)+(p&3)
// (matches the P^T B-fragment register order of the flash kernel).
__global__ void transpose_v(const unsigned short* __restrict__ v,
                            unsigned short* __restrict__ vt1,
                            unsigned short* __restrict__ vt2,
                            unsigned short* __restrict__ vt3) {
  __shared__ unsigned short Tt[64 * 72];
  const int tid = threadIdx.x;
  const int h = blockIdx.y;
  const int bx = blockIdx.x;
  const unsigned short* src = v + (size_t)h * 8192 * 64;
  unsigned short* dst;
  int dil, Nk, t0;
  if (bx < 32)      { dst = vt1; dil = 1; Nk = 2048; t0 = bx; }
  else if (bx < 96) { dst = vt2; dil = 2; Nk = 4096; t0 = bx - 32; }
  else              { dst = vt3; dil = 4; Nk = 2048; t0 = bx - 96; }
  dst += (size_t)h * 64 * Nk;
  const int j0 = t0 * 64;
#pragma unroll
  for (int it = 0; it < 2; ++it) {
    const int slot = tid + it * 256;
    const int jj = slot >> 3, c8 = (slot & 7) * 8;
    *(bf16x8*)&Tt[jj * 72 + c8] =
        *(const bf16x8*)&src[(size_t)(j0 + jj) * dil * 64 + c8];
  }
  __syncthreads();
  const int d = tid >> 2, pg = (tid & 3) * 16;
  union { bf16x8 v2[2]; unsigned short u[16]; } ob;
#pragma unroll
  for (int t = 0; t < 16; ++t) {
    const int pos = pg + t;
    const int w = pos & 31;
    const int jj = (pos & 32) | (((w >> 2) & 1) * 16 + (w >> 3) * 4 + (w & 3));
    ob.u[t] = Tt[jj * 72 + d];
  }
  *(bf16x8*)&dst[(size_t)d * Nk + j0 + pg] = ob.v2[0];
  *(bf16x8*)&dst[(size_t)d * Nk + j0 + pg + 8] = ob.v2[1];
}

// --------------------------- flash attention, all segments -----------------
// S^T = K.Q^T (A=K direct from global/L1, B=Q register-resident); O^T =
// V^T.P^T (A=V^T direct from global/L1, B=P^T built in-register from packed
// exp2 C-regs; vt key-perm makes layouts coincide). WG = 512 thr = 8 waves:
// wave w = (ks=w>>2, wq=w&3); wq-waves share identical K/V tiles -> L1 dedup.
// NO barriers / NO LDS in the main loop: waves free-run, 4 waves/SIMD hide
// the per-tile load->MFMA->exp2->MFMA chain. l via ones-A-frag MFMA.
// Epilogue (LDS, 33KB): waves 4-7 publish partial O^T/l; waves 0-3 add,
// divide by total 3l, transpose through LDS, store coalesced.
// Block mapping: even bx = seg2, odd bx = seg1/3.
__global__ __launch_bounds__(512, 2) void flash_all(
    const unsigned short* __restrict__ qkvb,
    const unsigned short* __restrict__ vt1, float* __restrict__ o1,
    const unsigned short* __restrict__ vt2, float* __restrict__ o2,
    const unsigned short* __restrict__ vt3, float* __restrict__ o3) {
  // Epilogue-only LDS: Wo f32[0,4096) | Wp f32[4096,8192) | lbuf f32 @8192.
  __shared__ float Sep[8192 + 64];

  // block -> (segment, head, q-tile): even bx = seg2; odd alternates seg1/seg3
  const int bx = blockIdx.x;
  int z, h, qt;
  if ((bx & 1) == 0) { const int i = bx >> 1; z = 1; h = i >> 4; qt = i & 15; }
  else { const int j = bx >> 1; z = (j & 1) ? 2 : 0; const int i = j >> 1; h = i >> 3; qt = i & 7; }
  const int Nk = (z == 1) ? 4096 : 2048;
  const int dil = 1 << z;
  const unsigned short* vt = (z == 0) ? vt1 : (z == 1) ? vt2 : vt3;
  float* o = (z == 0) ? o1 : (z == 1) ? o2 : o3;

  const int tid = threadIdx.x;
  const int wave = tid >> 6, lane = tid & 63;
  const int quad = lane >> 4, lc = lane & 15;
  const int ks = wave >> 2, wq = wave & 3;   // key-subset / q-subtile roles

  const unsigned short* qh = qkvb + (size_t)h * 8192 * 64;
  const unsigned short* kh = qkvb + (size_t)(16 + h) * 8192 * 64;
  const unsigned short* vh = vt + (size_t)h * 64 * Nk;

  // Q B-fragments: 4 m-blocks of 16 q (B[n=lc][k=quad*8+j], halves d<32,>=32)
  bf16x8 qf[4][2];
#pragma unroll
  for (int mb = 0; mb < 4; ++mb) {
    const size_t qrow = (size_t)(qt * 256 + wq * 64 + mb * 16 + lc) * dil;
    qf[mb][0] = *(const bf16x8*)&qh[qrow * 64 + quad * 8];
    qf[mb][1] = *(const bf16x8*)&qh[qrow * 64 + quad * 8 + 32];
  }

  // constant all-ones A fragment (bf16 1.0) for the row-sum (l) MFMA
  union { bf16x8 v; unsigned short u[8]; } one_u;
#pragma unroll
  for (int t = 0; t < 8; ++t) one_u.u[t] = 0x3F80;
  const bf16x8 vone = one_u.v;

  f32x4 oacc[4][4] = {};   // [mb][nb]  partial O^T C-tiles: row=d, col=q
  f32x4 lacc[4] = {};      // [mb]      partial l per q (all rows identical)

  // per-lane fragment pointers (bumped per tile; increments are uniform):
  //  K A-frag rows (kb + ks*32 + t2*16 + lc)*dil, d-chunk quad (lo) / 4+quad
  //  V A-frag rows nb*16+lc (d), key-chunk ks*4+quad within the tile
  const unsigned short* kp0 = kh + (size_t)((ks * 32 + lc) * dil) * 64 + quad * 8;
  const unsigned short* kp1 = kh + (size_t)((ks * 32 + 16 + lc) * dil) * 64 + quad * 8;
  const unsigned short* vp = vh + (size_t)lc * Nk + (ks * 4 + quad) * 8;
  const size_t kstep = (size_t)64 * dil * 64;   // shorts per 64-key hop (K)

  for (int kb = 0; kb < Nk; kb += 64) {
    // ---- K fragment loads first, V second: QK's implicit vmcnt wait
    // leaves the V loads in flight across the exp2 phase ----
    bf16x8 ka[2][2], va[4];
    ka[0][0] = *(const bf16x8*)(kp0);
    ka[0][1] = *(const bf16x8*)(kp0 + 32);
    ka[1][0] = *(const bf16x8*)(kp1);
    ka[1][1] = *(const bf16x8*)(kp1 + 32);
    va[0] = *(const bf16x8*)(vp);
    va[1] = *(const bf16x8*)(vp + (size_t)16 * Nk);
    va[2] = *(const bf16x8*)(vp + (size_t)32 * Nk);
    va[3] = *(const bf16x8*)(vp + (size_t)48 * Nk);
    kp0 += kstep; kp1 += kstep; vp += 64;

    // ---- S^T (this wave's 32-key subset) -> exp2 -> packed P^T frags ----
    union { unsigned int u[4]; bf16x8 v; } pb[4];
#pragma unroll
    for (int t2 = 0; t2 < 2; ++t2) {
#pragma unroll
      for (int mb = 0; mb < 4; ++mb) {
        f32x4 zz = {};
        zz = MFMA(ka[t2][0], qf[mb][0], zz);
        zz = MFMA(ka[t2][1], qf[mb][1], zz);
        const float e0 = EXP2(zz[0]);
        const float e1 = EXP2(zz[1]);
        const float e2 = EXP2(zz[2]);
        const float e3 = EXP2(zz[3]);
        unsigned int p01, p23;
        asm("v_cvt_pk_bf16_f32 %0, %1, %2" : "=v"(p01) : "v"(e0), "v"(e1));
        asm("v_cvt_pk_bf16_f32 %0, %1, %2" : "=v"(p23) : "v"(e2), "v"(e3));
        pb[mb].u[t2 * 2 + 0] = p01;
        pb[mb].u[t2 * 2 + 1] = p23;
      }
    }

    // ---- O^T += V^T.P^T ; l += 1.P^T (this wave's key subset only) ----
    __builtin_amdgcn_s_setprio(1);
#pragma unroll
    for (int nb = 0; nb < 4; ++nb) {
#pragma unroll
      for (int mb = 0; mb < 4; ++mb)
        oacc[mb][nb] = MFMA(va[nb], pb[mb].v, oacc[mb][nb]);
    }
#pragma unroll
    for (int mb = 0; mb < 4; ++mb) lacc[mb] = MFMA(vone, pb[mb].v, lacc[mb]);
    __builtin_amdgcn_s_setprio(0);
  }

  // ---- epilogue: pair-combine ks partials, O^T -> O via swizzled LDS ------
  float* Wo = Sep + wq * 16 * 64;          // waves 0-3 own regions
  float* Wp = Sep + 4096 + wq * 16 * 64;   // waves 4-7 partials
  float* lbuf = Sep + 8192;                // 64 partial-l floats
  const int g = lane >> 2, s4 = lane & 3;
#pragma unroll
  for (int mb = 0; mb < 4; ++mb) {
    if (wave >= 4) {
      // publish partial O^T tile (swizzled transposed layout) + l
#pragma unroll
      for (int nb = 0; nb < 4; ++nb) {
        const int c = nb * 4 + quad;
        const int cs = (c & 8) | ((c & 7) ^ (lc & 7));
        *(f32x4*)&Wp[lc * 64 + cs * 4] = oacc[mb][nb];
      }
      if (quad == 0) lbuf[wq * 16 + lc] = lacc[mb][0];
    }
    __syncthreads();
    if (wave < 4) {
      const float inv = 1.0f / (3.0f * (lacc[mb][0] + lbuf[wq * 16 + lc]));
#pragma unroll
      for (int nb = 0; nb < 4; ++nb) {
        const int c = nb * 4 + quad;
        const int cs = (c & 8) | ((c & 7) ^ (lc & 7));
        f32x4 val = oacc[mb][nb] + *(const f32x4*)&Wp[lc * 64 + cs * 4];
        val *= inv;
        *(f32x4*)&Wo[lc * 64 + cs * 4] = val;
      }
      // read back transposed (same-wave ds ordering via lgkmcnt)
      const size_t base = (size_t)(qt * 256 + wq * 64 + mb * 16 + g) * 1024 +
                          (size_t)h * 64 + s4 * 16;
#pragma unroll
      for (int c2 = 0; c2 < 4; ++c2) {
        const int c = s4 * 4 + c2;
        const int cs = (c & 8) | ((c & 7) ^ (g & 7));
        *(float4*)&o[base + c2 * 4] = *(const float4*)&Wo[g * 64 + cs * 4];
      }
    }
    __syncthreads();
  }
}

// ------------------- combine per-seg outputs -> bf16 a3 --------------------
__global__ void combine(const float* __restrict__ o1, const float* __restrict__ o2,
                        const float* __restrict__ o3,
                        unsigned short* __restrict__ a3b) {
  const int idx = blockIdx.x * 256 + threadIdx.x;   // 8192*128
  const int s = idx >> 7, e = (idx & 127) * 8;
  float acc[8] = {};
  if (s < 2048) {
    const float* p = &o1[(size_t)s * 1024 + e];
#pragma unroll
    for (int t = 0; t < 8; ++t) acc[t] += p[t];
  }
  if (!(s & 1)) {
    const float* p = &o2[(size_t)(s >> 1) * 1024 + e];
#pragma unroll
    for (int t = 0; t < 8; ++t) acc[t] += p[t];
  }
  if (!(s & 3)) {
    const float* p = &o3[(size_t)(s >> 2) * 1024 + e];
#pragma unroll
    for (int t = 0; t < 8; ++t) acc[t] += p[t];
  }
  union { bf16x8 v; unsigned short u[8]; } ob;
#pragma unroll
  for (int t = 0; t < 8; ++t) ob.u[t] = f2bf(acc[t]);
  *(bf16x8*)&a3b[(size_t)s * 1024 + e] = ob.v;
}

// ---------------------------------------------------------------------------
extern "C" void kernel_launch(void* const* d_in, const int* in_sizes, int n_in,
                              void* d_out, int out_size, void* d_ws, size_t ws_size,
                              hipStream_t stream) {
  const float* x     = (const float*)d_in[0];  // [8192][1024]
  const float* w_qkv = (const float*)d_in[1];  // [3072][1024]
  const float* b_qkv = (const float*)d_in[2];  // [3072]
  const float* w_out = (const float*)d_in[3];  // [1024][1024]
  const float* b_out = (const float*)d_in[4];  // [1024]
  float* out = (float*)d_out;                  // [8192][1024] f32

  char* ws = (char*)d_ws;
  unsigned short* qkvb  = (unsigned short*)(ws);             // Q,K,V: 50,331,648 B
  // V third of qkvb (offset 33,554,432) doubles as o1/o3 after transpose_v:
  float*          o1    = (float*)(ws + 33554432);           //  8,388,608 B (over V)
  float*          o3    = (float*)(ws + 41943040);           //  8,388,608 B (over V)
  unsigned short* vt1   = (unsigned short*)(ws + 50331648);  //  4,194,304 B
  unsigned short* vt2   = (unsigned short*)(ws + 54525952);  //  8,388,608 B
  unsigned short* vt3   = (unsigned short*)(ws + 62914560);  //  4,194,304 B
  float*          o2    = (float*)(ws + 67108864);           // 16,777,216 B
  unsigned short* wqkvb = (unsigned short*)(ws + 83886080);  //  6,291,456 B
  unsigned short* woutb = (unsigned short*)(ws + 90177536);  //  2,097,152 B
  unsigned short* xb    = (unsigned short*)(ws + 92274688);  // 16,777,216 B (reused a3b)
  unsigned short* a3b   = xb;

  cvt_f32_bf16<<<dim3(8388608 / 8 / 256), dim3(256), 0, stream>>>(x, xb, 8388608 / 8);
  cvt_f32_bf16<<<dim3(3145728 / 8 / 256), dim3(256), 0, stream>>>(w_qkv, wqkvb, 3145728 / 8);
  cvt_f32_bf16<<<dim3(1048576 / 8 / 256), dim3(256), 0, stream>>>(w_out, woutb, 1048576 / 8);

  // QKV projection -> [3][16][8192][64] (Q pre-scaled by log2e/8)
  gemm_bt<0><<<dim3(64, 24), dim3(256), 0, stream>>>(xb, wqkvb, b_qkv, qkvb, 3072, 1024);

  // V -> key-permuted transposed dilation copies
  transpose_v<<<dim3(128, 16), dim3(256), 0, stream>>>(qkvb + (size_t)32 * 8192 * 64,
                                                       vt1, vt2, vt3);

  // all 3 attention segments: 512 blocks x 512 threads (2 blocks/CU,
  // 16 waves/CU; wave pairs split the 64-key tile's two 32-key subsets)
  flash_all<<<dim3(512), dim3(512), 0, stream>>>(qkvb, vt1, o1, vt2, o2, vt3, o3);

  // sum segment outputs (mean /3 and /l already folded) -> bf16
  combine<<<dim3(4096), dim3(256), 0, stream>>>(o1, o2, o3, a3b);

  // output projection: out = a3 . woutb^T + b_out   (f32 out)
  gemm_bt<1><<<dim3(64, 8), dim3(256), 0, stream>>>(a3b, woutb, b_out, out, 1024, 1024);
}

// Round 9
// 335.165 us; speedup vs baseline: 1.3236x; 1.3236x over previous
//
#include <hip/hip_runtime.h>

// ---------------------------------------------------------------------------
// RingDilatedAttentionSDPA: B=1, S=8192, E=1024, H=16, D=64
// segments: (len=2048,dil=1), (4096,2), (8192->2048,4); mean of scattered outs
// Pipeline: cvt f32->bf16 ; QKV GEMM -> Q(pre-scaled log2e/8),K,V [h][s][d] ;
// transpose_v -> 3 key-permuted V^T dilation copies ; single flash launch
// computing S^T=K.Q^T and O^T=V^T.P^T (Q register-resident B-operand; packed
// exp2 C-regs ARE the P^T B-frag thanks to the vt key permutation — no P LDS
// round-trip; XOR-swizzled conflict-free LDS tiles) ; combine ; out GEMM.
// R9: BYTE-EXACT R0 revert (the 334.9us passing artifact). R5-R8 all failed
// nondeterministically (pytest ~3e-2 vs JSON-stage 468); bisection isolated
// v_cvt_pk_bf16_f32-consuming-EXP2 inline asm as the common factor — the
// gfx950 TRANS-op hazard recognizer doesn't protect INLINEASM consumers of
// v_exp_f32 results (rule-18 family). R0's perm-based pack consumes EXP2 via
// compiler-generated v_add/v_perm -> hazard-safe. NO deltas this round:
// re-anchor on the known-passing baseline.
// ---------------------------------------------------------------------------

typedef __attribute__((ext_vector_type(8))) short bf16x8;   // 8 bf16 in 4 VGPRs
typedef __attribute__((ext_vector_type(4))) float f32x4;

#define MFMA(a, b, c) __builtin_amdgcn_mfma_f32_16x16x32_bf16((a), (b), (c), 0, 0, 0)

#if __has_builtin(__builtin_amdgcn_exp2f)
#define EXP2(x) __builtin_amdgcn_exp2f(x)
#else
#define EXP2(x) exp2f(x)
#endif

static __device__ __forceinline__ unsigned short f2bf(float f) {
  unsigned int u = __float_as_uint(f);
  unsigned int r = (u + 0x7FFFu + ((u >> 16) & 1u)) >> 16;  // RNE
  return (unsigned short)r;
}

// ---------------------------- f32 -> bf16 convert --------------------------
__global__ void cvt_f32_bf16(const float* __restrict__ in,
                             unsigned short* __restrict__ out, int n8) {
  int i = blockIdx.x * blockDim.x + threadIdx.x;
  if (i >= n8) return;
  const float4* p = (const float4*)in + (size_t)i * 2;
  float4 a = p[0];
  float4 b = p[1];
  union { bf16x8 v; unsigned short u[8]; } o;
  o.u[0] = f2bf(a.x); o.u[1] = f2bf(a.y); o.u[2] = f2bf(a.z); o.u[3] = f2bf(a.w);
  o.u[4] = f2bf(b.x); o.u[5] = f2bf(b.y); o.u[6] = f2bf(b.z); o.u[7] = f2bf(b.w);
  *((bf16x8*)out + i) = o.v;
}

// ------------------------------- GEMM (C = A.B^T + bias) -------------------
// EPILOGUE 0: qkv [3][16][8192][64] bf16, Q scaled by log2e/8; 1: f32 rowmaj.
template <int EPILOGUE>
__global__ __launch_bounds__(256, 2) void gemm_bt(
    const unsigned short* __restrict__ A, const unsigned short* __restrict__ B,
    const float* __restrict__ bias, void* __restrict__ Cout, int N, int K) {
  __shared__ unsigned short At[128 * 32];
  __shared__ unsigned short Bt[128 * 32];
  const int tid = threadIdx.x;
  const int wave = tid >> 6, lane = tid & 63;
  const int quad = lane >> 4, lc = lane & 15;
  const int wm = (wave >> 1) * 64, wn = (wave & 1) * 64;
  const int m0 = blockIdx.x * 128, n0 = blockIdx.y * 128;

  f32x4 acc[4][4] = {};

  for (int k0 = 0; k0 < K; k0 += 32) {
    __syncthreads();
#pragma unroll
    for (int issue = 0; issue < 2; ++issue) {
      const int cbase = issue * 256 + wave * 64;
      const int c = cbase + lane;
      const int row = c >> 2, col8 = (c & 3) * 8;   // 128 rows x 32 cols
      __builtin_amdgcn_global_load_lds(
          (const __attribute__((address_space(1))) void*)&A[(size_t)(m0 + row) * K + k0 + col8],
          (__attribute__((address_space(3))) void*)&At[cbase * 8], 16, 0, 0);
      __builtin_amdgcn_global_load_lds(
          (const __attribute__((address_space(1))) void*)&B[(size_t)(n0 + row) * K + k0 + col8],
          (__attribute__((address_space(3))) void*)&Bt[cbase * 8], 16, 0, 0);
    }
    __syncthreads();
    bf16x8 af[4], bfr[4];
#pragma unroll
    for (int t = 0; t < 4; ++t)
      af[t] = *(const bf16x8*)&At[(wm + t * 16 + lc) * 32 + quad * 8];
#pragma unroll
    for (int t = 0; t < 4; ++t)
      bfr[t] = *(const bf16x8*)&Bt[(wn + t * 16 + lc) * 32 + quad * 8];
#pragma unroll
    for (int i = 0; i < 4; ++i)
#pragma unroll
      for (int j = 0; j < 4; ++j)
        acc[i][j] = MFMA(af[i], bfr[j], acc[i][j]);
  }

#pragma unroll
  for (int i = 0; i < 4; ++i) {
#pragma unroll
    for (int j = 0; j < 4; ++j) {
      const int gcol = n0 + wn + j * 16 + lc;
      const float bs = bias[gcol];
#pragma unroll
      for (int r = 0; r < 4; ++r) {
        const int grow = m0 + wm + i * 16 + quad * 4 + r;
        const float v = acc[i][j][r] + bs;
        if (EPILOGUE == 0) {
          const int which = gcol >> 10, rem = gcol & 1023;
          const int hh = rem >> 6, d = rem & 63;
          // Q gets 1/sqrt(D) * log2(e) folded in (exp2 softmax downstream)
          const float vs = (which == 0) ? v * 0.18033688f : v;
          ((unsigned short*)Cout)[(((size_t)(which * 16 + hh)) * 8192 + grow) * 64 + d] = f2bf(vs);
        } else {
          ((float*)Cout)[(size_t)grow * N + gcol] = v;
        }
      }
    }
  }
}

// ---------------- V transpose: [h][s][d] -> key-permuted [h][d][n] ---------
// perm within each 32-block: position p holds key 16*((p>>2)&1)+4*(p>>3)+(p&3)
// (matches the P^T B-fragment register order of the flash kernel).
__global__ void transpose_v(const unsigned short* __restrict__ v,
                            unsigned short* __restrict__ vt1,
                            unsigned short* __restrict__ vt2,
                            unsigned short* __restrict__ vt3) {
  __shared__ unsigned short Tt[64 * 72];
  const int tid = threadIdx.x;
  const int h = blockIdx.y;
  const int bx = blockIdx.x;
  const unsigned short* src = v + (size_t)h * 8192 * 64;
  unsigned short* dst;
  int dil, Nk, t0;
  if (bx < 32)      { dst = vt1; dil = 1; Nk = 2048; t0 = bx; }
  else if (bx < 96) { dst = vt2; dil = 2; Nk = 4096; t0 = bx - 32; }
  else              { dst = vt3; dil = 4; Nk = 2048; t0 = bx - 96; }
  dst += (size_t)h * 64 * Nk;
  const int j0 = t0 * 64;
#pragma unroll
  for (int it = 0; it < 2; ++it) {
    const int slot = tid + it * 256;
    const int jj = slot >> 3, c8 = (slot & 7) * 8;
    *(bf16x8*)&Tt[jj * 72 + c8] =
        *(const bf16x8*)&src[(size_t)(j0 + jj) * dil * 64 + c8];
  }
  __syncthreads();
  const int d = tid >> 2, pg = (tid & 3) * 16;
  union { bf16x8 v2[2]; unsigned short u[16]; } ob;
#pragma unroll
  for (int t = 0; t < 16; ++t) {
    const int pos = pg + t;
    const int w = pos & 31;
    const int jj = (pos & 32) | (((w >> 2) & 1) * 16 + (w >> 3) * 4 + (w & 3));
    ob.u[t] = Tt[jj * 72 + d];
  }
  *(bf16x8*)&dst[(size_t)d * Nk + j0 + pg] = ob.v2[0];
  *(bf16x8*)&dst[(size_t)d * Nk + j0 + pg + 8] = ob.v2[1];
}

// --------------------------- flash attention, all segments -----------------
// S^T = K.Q^T (A=K from LDS, B=Q register-resident); O^T = V^T.P^T (A=V^T
// from LDS, B=P^T built in-register from packed exp2 C-regs — key perm in vt
// makes the layouts coincide). WG = 256 q (4 waves x 64 q), KV tile = 64 keys.
// LDS: K tile + V^T tile, XOR-swizzled 16B chunks (chunk^ = c ^ (row&7)) ->
// conflict-free b128; same 16KB reused for the O^T->O epilogue transpose.
// l via ones-A-frag MFMA. Block mapping: even bx = seg2, odd bx = seg1/3.
__global__ __launch_bounds__(256, 2) void flash_all(
    const unsigned short* __restrict__ qkvb,
    const unsigned short* __restrict__ vt1, float* __restrict__ o1,
    const unsigned short* __restrict__ vt2, float* __restrict__ o2,
    const unsigned short* __restrict__ vt3, float* __restrict__ o3) {
  __shared__ unsigned short Smem[2 * 64 * 64];  // Kt | Vt ; epilogue: f32 O^T
  unsigned short* Kt = Smem;
  unsigned short* Vt = Smem + 64 * 64;

  // block -> (segment, head, q-tile): even bx = seg2; odd alternates seg1/seg3
  const int bx = blockIdx.x;
  int z, h, qt;
  if ((bx & 1) == 0) { const int i = bx >> 1; z = 1; h = i >> 4; qt = i & 15; }
  else { const int j = bx >> 1; z = (j & 1) ? 2 : 0; const int i = j >> 1; h = i >> 3; qt = i & 7; }
  const int Nk = (z == 1) ? 4096 : 2048;
  const int dil = 1 << z;
  const unsigned short* vt = (z == 0) ? vt1 : (z == 1) ? vt2 : vt3;
  float* o = (z == 0) ? o1 : (z == 1) ? o2 : o3;

  const int tid = threadIdx.x;
  const int wave = tid >> 6, lane = tid & 63;
  const int quad = lane >> 4, lc = lane & 15;

  const unsigned short* qh = qkvb + (size_t)h * 8192 * 64;
  const unsigned short* kh = qkvb + (size_t)(16 + h) * 8192 * 64;
  const unsigned short* vh = vt + (size_t)h * 64 * Nk;

  // Q B-fragments: 4 m-blocks of 16 q (B[n=lc][k=quad*8+j], halves d<32,>=32)
  bf16x8 qf[4][2];
#pragma unroll
  for (int mb = 0; mb < 4; ++mb) {
    const size_t qrow = (size_t)(qt * 256 + wave * 64 + mb * 16 + lc) * dil;
    qf[mb][0] = *(const bf16x8*)&qh[qrow * 64 + quad * 8];
    qf[mb][1] = *(const bf16x8*)&qh[qrow * 64 + quad * 8 + 32];
  }

  // constant all-ones A fragment (bf16 1.0) for the row-sum (l) MFMA
  union { bf16x8 v; unsigned short u[8]; } one_u;
#pragma unroll
  for (int t = 0; t < 8; ++t) one_u.u[t] = 0x3F80;
  const bf16x8 vone = one_u.v;

  f32x4 oacc[4][4] = {};   // [mb][nb]  O^T C-tiles: row=d, col=q
  f32x4 lacc[4] = {};      // [mb]      l per q (all rows identical)

  // staging: 512 slots of 16B per tile-pair; swizzled chunk = scol ^ (row&7)
  const int srow = tid >> 3, scol = tid & 7;
  const int swz = (scol ^ (srow & 7)) * 8;

  bf16x8 kg0 = *(const bf16x8*)&kh[(size_t)(srow * dil) * 64 + scol * 8];
  bf16x8 kg1 = *(const bf16x8*)&kh[(size_t)((srow + 32) * dil) * 64 + scol * 8];
  bf16x8 vg0 = *(const bf16x8*)&vh[(size_t)srow * Nk + scol * 8];
  bf16x8 vg1 = *(const bf16x8*)&vh[(size_t)(srow + 32) * Nk + scol * 8];

  for (int kb = 0; kb < Nk; kb += 64) {
    __syncthreads();
    *(bf16x8*)&Kt[srow * 64 + swz] = kg0;
    *(bf16x8*)&Kt[(srow + 32) * 64 + swz] = kg1;
    *(bf16x8*)&Vt[srow * 64 + swz] = vg0;
    *(bf16x8*)&Vt[(srow + 32) * 64 + swz] = vg1;
    __syncthreads();

    if (kb + 64 < Nk) {   // prefetch next tile into registers
      const int nk = kb + 64;
      kg0 = *(const bf16x8*)&kh[(size_t)((nk + srow) * dil) * 64 + scol * 8];
      kg1 = *(const bf16x8*)&kh[(size_t)((nk + srow + 32) * dil) * 64 + scol * 8];
      vg0 = *(const bf16x8*)&vh[(size_t)srow * Nk + nk + scol * 8];
      vg1 = *(const bf16x8*)&vh[(size_t)(srow + 32) * Nk + nk + scol * 8];
    }

#pragma unroll
    for (int ks = 0; ks < 2; ++ks) {         // two 32-key subsets
      // ---- S^T tiles: D[m=key][n=q] = K.Q^T ----
      f32x4 st[2][4];
#pragma unroll
      for (int t = 0; t < 2; ++t) {
        const int row = (ks * 2 + t) * 16 + lc;
        const bf16x8 ka0 = *(const bf16x8*)&Kt[row * 64 + ((quad ^ (lc & 7)) * 8)];
        const bf16x8 ka1 = *(const bf16x8*)&Kt[row * 64 + (((4 + quad) ^ (lc & 7)) * 8)];
#pragma unroll
        for (int mb = 0; mb < 4; ++mb) {
          f32x4 zz = {};
          zz = MFMA(ka0, qf[mb][0], zz);
          st[t][mb] = MFMA(ka1, qf[mb][1], zz);
        }
      }

      // ---- p = exp2(s); pack -> P^T B-frags (register order == vt key perm)
      bf16x8 pb[4];
#pragma unroll
      for (int mb = 0; mb < 4; ++mb) {
        union { bf16x8 v; unsigned int u[4]; } pu;
#pragma unroll
        for (int t = 0; t < 2; ++t) {
          const unsigned int a0 = __float_as_uint(EXP2(st[t][mb][0])) + 0x8000u;
          const unsigned int a1 = __float_as_uint(EXP2(st[t][mb][1])) + 0x8000u;
          const unsigned int a2 = __float_as_uint(EXP2(st[t][mb][2])) + 0x8000u;
          const unsigned int a3 = __float_as_uint(EXP2(st[t][mb][3])) + 0x8000u;
          pu.u[t * 2 + 0] = __builtin_amdgcn_perm(a1, a0, 0x07060302u);
          pu.u[t * 2 + 1] = __builtin_amdgcn_perm(a3, a2, 0x07060302u);
        }
        pb[mb] = pu.v;
      }

      // ---- O^T += V^T.P^T ; l += 1.P^T ----
#pragma unroll
      for (int nb = 0; nb < 4; ++nb) {
        const int vrow = nb * 16 + lc;
        const bf16x8 va = *(const bf16x8*)&Vt[vrow * 64 + (((ks * 4 + quad) ^ (lc & 7)) * 8)];
#pragma unroll
        for (int mb = 0; mb < 4; ++mb)
          oacc[mb][nb] = MFMA(va, pb[mb], oacc[mb][nb]);
      }
#pragma unroll
      for (int mb = 0; mb < 4; ++mb) lacc[mb] = MFMA(vone, pb[mb], lacc[mb]);
    }
  }

  // ---- epilogue: O^T -> O via swizzled LDS transpose, coalesced stores ----
  __syncthreads();                       // all waves done reading Kt/Vt
  float* W = (float*)Smem + wave * 16 * 64;   // per-wave 16q x 64d region
  const int g = lane >> 2, s4 = lane & 3;
#pragma unroll
  for (int mb = 0; mb < 4; ++mb) {
    const float inv = 1.0f / (3.0f * lacc[mb][0]);   // fold mean over 3 segs
#pragma unroll
    for (int nb = 0; nb < 4; ++nb) {
      const int c = nb * 4 + quad;
      const int cs = (c & 8) | ((c & 7) ^ (lc & 7));
      f32x4 val = oacc[mb][nb];
      val *= inv;
      *(f32x4*)&W[lc * 64 + cs * 4] = val;
    }
    // read back transposed (same-wave ds ordering via lgkmcnt)
    const size_t base = (size_t)(qt * 256 + wave * 64 + mb * 16 + g) * 1024 +
                        (size_t)((bx & 1) ? ((bx >> 1) >> 1) >> 3 : (bx >> 1) >> 4) * 64 + s4 * 16;
#pragma unroll
    for (int c2 = 0; c2 < 4; ++c2) {
      const int c = s4 * 4 + c2;
      const int cs = (c & 8) | ((c & 7) ^ (g & 7));
      *(float4*)&o[base + c2 * 4] = *(const float4*)&W[g * 64 + cs * 4];
    }
  }
}

// ------------------- combine per-seg outputs -> bf16 a3 --------------------
__global__ void combine(const float* __restrict__ o1, const float* __restrict__ o2,
                        const float* __restrict__ o3,
                        unsigned short* __restrict__ a3b) {
  const int idx = blockIdx.x * 256 + threadIdx.x;   // 8192*128
  const int s = idx >> 7, e = (idx & 127) * 8;
  float acc[8] = {};
  if (s < 2048) {
    const float* p = &o1[(size_t)s * 1024 + e];
#pragma unroll
    for (int t = 0; t < 8; ++t) acc[t] += p[t];
  }
  if (!(s & 1)) {
    const float* p = &o2[(size_t)(s >> 1) * 1024 + e];
#pragma unroll
    for (int t = 0; t < 8; ++t) acc[t] += p[t];
  }
  if (!(s & 3)) {
    const float* p = &o3[(size_t)(s >> 2) * 1024 + e];
#pragma unroll
    for (int t = 0; t < 8; ++t) acc[t] += p[t];
  }
  union { bf16x8 v; unsigned short u[8]; } ob;
#pragma unroll
  for (int t = 0; t < 8; ++t) ob.u[t] = f2bf(acc[t]);
  *(bf16x8*)&a3b[(size_t)s * 1024 + e] = ob.v;
}

// ---------------------------------------------------------------------------
extern "C" void kernel_launch(void* const* d_in, const int* in_sizes, int n_in,
                              void* d_out, int out_size, void* d_ws, size_t ws_size,
                              hipStream_t stream) {
  const float* x     = (const float*)d_in[0];  // [8192][1024]
  const float* w_qkv = (const float*)d_in[1];  // [3072][1024]
  const float* b_qkv = (const float*)d_in[2];  // [3072]
  const float* w_out = (const float*)d_in[3];  // [1024][1024]
  const float* b_out = (const float*)d_in[4];  // [1024]
  float* out = (float*)d_out;                  // [8192][1024] f32

  char* ws = (char*)d_ws;
  unsigned short* qkvb  = (unsigned short*)(ws);             // Q,K,V: 50,331,648 B
  // V third of qkvb (offset 33,554,432) doubles as o1/o3 after transpose_v:
  float*          o1    = (float*)(ws + 33554432);           //  8,388,608 B (over V)
  float*          o3    = (float*)(ws + 41943040);           //  8,388,608 B (over V)
  unsigned short* vt1   = (unsigned short*)(ws + 50331648);  //  4,194,304 B
  unsigned short* vt2   = (unsigned short*)(ws + 54525952);  //  8,388,608 B
  unsigned short* vt3   = (unsigned short*)(ws + 62914560);  //  4,194,304 B
  float*          o2    = (float*)(ws + 67108864);           // 16,777,216 B
  unsigned short* wqkvb = (unsigned short*)(ws + 83886080);  //  6,291,456 B
  unsigned short* woutb = (unsigned short*)(ws + 90177536);  //  2,097,152 B
  unsigned short* xb    = (unsigned short*)(ws + 92274688);  // 16,777,216 B (reused a3b)
  unsigned short* a3b   = xb;

  cvt_f32_bf16<<<dim3(8388608 / 8 / 256), dim3(256), 0, stream>>>(x, xb, 8388608 / 8);
  cvt_f32_bf16<<<dim3(3145728 / 8 / 256), dim3(256), 0, stream>>>(w_qkv, wqkvb, 3145728 / 8);
  cvt_f32_bf16<<<dim3(1048576 / 8 / 256), dim3(256), 0, stream>>>(w_out, woutb, 1048576 / 8);

  // QKV projection -> [3][16][8192][64] (Q pre-scaled by log2e/8)
  gemm_bt<0><<<dim3(64, 24), dim3(256), 0, stream>>>(xb, wqkvb, b_qkv, qkvb, 3072, 1024);

  // V -> key-permuted transposed dilation copies
  transpose_v<<<dim3(128, 16), dim3(256), 0, stream>>>(qkvb + (size_t)32 * 8192 * 64,
                                                       vt1, vt2, vt3);

  // all 3 attention segments, balanced 512-block launch (2 blocks/CU)
  flash_all<<<dim3(512), dim3(256), 0, stream>>>(qkvb, vt1, o1, vt2, o2, vt3, o3);

  // sum segment outputs (mean /3 and /l already folded) -> bf16
  combine<<<dim3(4096), dim3(256), 0, stream>>>(o1, o2, o3, a3b);

  // output projection: out = a3 . woutb^T + b_out   (f32 out)
  gemm_bt<1><<<dim3(64, 8), dim3(256), 0, stream>>>(a3b, woutb, b_out, out, 1024, 1024);
}